// Round 5
// baseline (549.191 us; speedup 1.0000x reference)
//
#include <hip/hip_runtime.h>
#include <stdint.h>

// AWQ 4-bit fused dequant GEMM: out[M,N] = x[M,K] @ W[N,K]^T + bias
// fp16 MFMA 16x16x32. BM=BN=256, BK=64, 512 threads (8 waves, 2x4 of 128x64).
// 8-phase-per-tile schedule (4 phases x {work | bar | lgkm0 | prio | 16 MFMA |
// prio | bar}), raw s_barrier (loads stay in flight), dequant staging sliced
// across phases, double-buffered 128 KB LDS, XOR swizzle, XCD chunk swizzle.

#define BM 256
#define BN 256
#define BK 64

typedef _Float16 f16x2 __attribute__((ext_vector_type(2)));
typedef _Float16 f16x8 __attribute__((ext_vector_type(8)));
typedef float f32x4 __attribute__((ext_vector_type(4)));

__global__ __launch_bounds__(512, 2) void awq_gemm_kernel(
    const float* __restrict__ x,
    const int*   __restrict__ qw,
    const int*   __restrict__ qz,
    const float* __restrict__ sc,
    const float* __restrict__ bias,
    float*       __restrict__ out,
    int M, int N, int K)
{
    extern __shared__ __align__(16) unsigned short lds[];
    unsigned short* As = lds;                    // [2][BM*BK]
    unsigned short* Bs = lds + 2 * BM * BK;      // [2][BN*BK]

    const int tid  = threadIdx.x;
    const int lane = tid & 63;
    const int wave = tid >> 6;            // 0..7
    const int wr   = wave >> 2;           // 0..1 -> 128-row half
    const int wc   = wave & 3;            // 0..3 -> 64-col quarter
    const int lrow = lane & 15;
    const int lko  = (lane >> 4) << 3;    // k chunk 0,8,16,24
    const int swr  = (lrow & 7) << 3;     // frag-read XOR swizzle

    // XCD-aware chunked swizzle (512 blocks, %8==0 -> bijective)
    const int cpx = gridDim.x >> 3;
    const int bid = (blockIdx.x & 7) * cpx + (blockIdx.x >> 3);
    const int ntn = N / BN;               // 16
    const int m0 = (bid / ntn) * BM;
    const int n0 = (bid % ntn) * BN;

    const int ngrp = K >> 7;              // 32
    const int nzw  = ngrp >> 3;           // 4
    const int kw   = K >> 3;              // int32 per qweight row
    const int NT   = K / BK;              // 64

    // staging map: 2 threads per row, each owns a 32-k half
    const int r_s = tid >> 1;             // 0..255
    const int kh  = tid & 1;
    const int sws = (r_s & 7) << 3;       // staging XOR swizzle

    f32x4 acc[8][4];
    #pragma unroll
    for (int m = 0; m < 8; ++m)
        #pragma unroll
        for (int n = 0; n < 4; ++n)
            #pragma unroll
            for (int e = 0; e < 4; ++e) acc[m][n][e] = 0.f;

    // prefetch registers (tile t+1 raw data)
    float4   a32[8];
    uint32_t bq[4];
    float    bs_;
    uint32_t bz_;

    auto LOADA = [&](int kt) {
        const float* p = x + (size_t)(m0 + r_s) * K + kt + kh * 32;
        #pragma unroll
        for (int i = 0; i < 8; ++i)
            a32[i] = *reinterpret_cast<const float4*>(p + 4 * i);
    };
    auto LOADB = [&](int kt) {
        const int4* p = reinterpret_cast<const int4*>(
            qw + (size_t)(n0 + r_s) * kw + (kt >> 3) + kh * 4);
        int4 v = *p;
        bq[0] = v.x; bq[1] = v.y; bq[2] = v.z; bq[3] = v.w;
        int grp = kt >> 7;
        bs_ = sc[(size_t)(n0 + r_s) * ngrp + grp];
        bz_ = ((uint32_t)qz[(size_t)(n0 + r_s) * nzw + (grp >> 3)] >> ((grp & 7) << 2)) & 0xF;
    };
    // one 8-float chunk of A -> fp16 pair-permuted -> LDS
    auto WA = [&](unsigned short* dst, int c) {
        uint4 o;
        o.x = __builtin_bit_cast(uint32_t, __builtin_amdgcn_cvt_pkrtz(a32[2*c].x, a32[2*c+1].x));
        o.y = __builtin_bit_cast(uint32_t, __builtin_amdgcn_cvt_pkrtz(a32[2*c].y, a32[2*c+1].y));
        o.z = __builtin_bit_cast(uint32_t, __builtin_amdgcn_cvt_pkrtz(a32[2*c].z, a32[2*c+1].z));
        o.w = __builtin_bit_cast(uint32_t, __builtin_amdgcn_cvt_pkrtz(a32[2*c].w, a32[2*c+1].w));
        int kcol = kh * 32 + 8 * c;
        *reinterpret_cast<uint4*>(&dst[r_s * BK + (kcol ^ sws)]) = o;
    };
    // one qweight word (8 nibbles) -> dequant fp16 -> LDS
    auto WB = [&](unsigned short* dst, int j) {
        _Float16 hs = (_Float16)bs_;
        _Float16 hz = (_Float16)(1024.0f + (float)bz_);  // <=1039: exact in fp16
        f16x2 s2 = {hs, hs};
        f16x2 z2 = {hz, hz};
        const uint32_t MK = 0x000F000Fu, MG = 0x64006400u;
        uint32_t u = bq[j];
        uint32_t t0 = (u & MK) | MG;
        uint32_t t1 = ((u >> 4) & MK) | MG;
        uint32_t t2 = ((u >> 8) & MK) | MG;
        uint32_t t3 = ((u >> 12) & MK) | MG;
        f16x2 w0 = (__builtin_bit_cast(f16x2, t0) - z2) * s2;
        f16x2 w1 = (__builtin_bit_cast(f16x2, t1) - z2) * s2;
        f16x2 w2 = (__builtin_bit_cast(f16x2, t2) - z2) * s2;
        f16x2 w3 = (__builtin_bit_cast(f16x2, t3) - z2) * s2;
        uint4 o;
        o.x = __builtin_bit_cast(uint32_t, w0);
        o.y = __builtin_bit_cast(uint32_t, w1);
        o.z = __builtin_bit_cast(uint32_t, w2);
        o.w = __builtin_bit_cast(uint32_t, w3);
        int kcol = kh * 32 + 8 * j;
        *reinterpret_cast<uint4*>(&dst[r_s * BK + (kcol ^ sws)]) = o;
    };

    f16x8 af[4], bf0[4], bf1[4];
    auto RDA = [&](const unsigned short* Ab, f16x8* a, int mh, int kk) {
        #pragma unroll
        for (int m = 0; m < 4; ++m) {
            int arow = wr * 128 + (mh * 4 + m) * 16 + lrow;
            int idx = arow * BK + ((kk * 32 + lko) ^ swr);
            a[m] = __builtin_bit_cast(f16x8, *reinterpret_cast<const uint4*>(&Ab[idx]));
        }
    };
    auto RDB = [&](const unsigned short* Bb, f16x8* b, int kk) {
        #pragma unroll
        for (int n = 0; n < 4; ++n) {
            int brow = wc * 64 + n * 16 + lrow;
            int idx = brow * BK + ((kk * 32 + lko) ^ swr);
            b[n] = __builtin_bit_cast(f16x8, *reinterpret_cast<const uint4*>(&Bb[idx]));
        }
    };

#define PHASE(AF, BF, MH)                                                     \
    __builtin_amdgcn_s_barrier();                                             \
    asm volatile("s_waitcnt lgkmcnt(0)" ::: "memory");                        \
    __builtin_amdgcn_sched_barrier(0);                                        \
    __builtin_amdgcn_s_setprio(1);                                            \
    _Pragma("unroll")                                                         \
    for (int m_ = 0; m_ < 4; ++m_)                                            \
        _Pragma("unroll")                                                     \
        for (int n_ = 0; n_ < 4; ++n_)                                        \
            acc[(MH)*4 + m_][n_] = __builtin_amdgcn_mfma_f32_16x16x32_f16(    \
                AF[m_], BF[n_], acc[(MH)*4 + m_][n_], 0, 0, 0);               \
    __builtin_amdgcn_s_setprio(0);                                            \
    __builtin_amdgcn_s_barrier();

    // prologue: load + stage tile 0 into buf 0
    LOADA(0); LOADB(0);
    {
        unsigned short* Aw = As;
        unsigned short* Bw = Bs;
        #pragma unroll
        for (int c = 0; c < 4; ++c) WA(Aw, c);
        #pragma unroll
        for (int j = 0; j < 4; ++j) WB(Bw, j);
    }
    __syncthreads();

    for (int t = 0; t < NT; ++t) {
        const int buf = t & 1;
        const unsigned short* Ab = As + buf * (BM * BK);
        const unsigned short* Bb = Bs + buf * (BN * BK);
        unsigned short* Aw = As + (buf ^ 1) * (BM * BK);
        unsigned short* Bw = Bs + (buf ^ 1) * (BN * BK);
        const bool pf = (t + 1 < NT);

        // ---- P0: issue next-tile global loads; read frags (mh0,kk0)+(B kk0)
        if (pf) { LOADA((t + 1) * BK); LOADB((t + 1) * BK); }
        RDB(Bb, bf0, 0);
        RDA(Ab, af, 0, 0);
        PHASE(af, bf0, 0)

        // ---- P1: read frags (mh1,kk0); stage slices A0,A1,B0,B1
        RDA(Ab, af, 1, 0);
        if (pf) { WA(Aw, 0); WA(Aw, 1); WB(Bw, 0); WB(Bw, 1); }
        PHASE(af, bf0, 1)

        // ---- P2: read frags (mh0,kk1)+(B kk1); stage slices A2,A3,B2
        RDB(Bb, bf1, 1);
        RDA(Ab, af, 0, 1);
        if (pf) { WA(Aw, 2); WA(Aw, 3); WB(Bw, 2); }
        PHASE(af, bf1, 0)

        // ---- P3: read frags (mh1,kk1); stage slice B3
        RDA(Ab, af, 1, 1);
        if (pf) { WB(Bw, 3); }
        PHASE(af, bf1, 1)
    }
#undef PHASE

    // epilogue: C frag mapping col=lane&15, row=(lane>>4)*4+e
    const int r4 = (lane >> 4) << 2;
    #pragma unroll
    for (int n = 0; n < 4; ++n) {
        int col = n0 + wc * 64 + n * 16 + lrow;
        float bv = bias[col];
        #pragma unroll
        for (int m = 0; m < 8; ++m) {
            size_t rbase = (size_t)(m0 + wr * 128 + m * 16 + r4) * N + col;
            #pragma unroll
            for (int e = 0; e < 4; ++e)
                __builtin_nontemporal_store(acc[m][n][e] + bv, &out[rbase + (size_t)e * N]);
        }
    }
}

extern "C" void kernel_launch(void* const* d_in, const int* in_sizes, int n_in,
                              void* d_out, int out_size, void* d_ws, size_t ws_size,
                              hipStream_t stream) {
    const float* x   = (const float*)d_in[0];
    const int*   qwp = (const int*)d_in[1];
    const int*   qzp = (const int*)d_in[2];
    const float* scp = (const float*)d_in[3];
    const float* bp  = (const float*)d_in[4];
    float* outp = (float*)d_out;

    const int N = in_sizes[4];                 // 4096 (O)
    const int K = (in_sizes[1] / N) * 8;       // 4096 (I)
    const int M = in_sizes[0] / K;             // 8192 (B)

    dim3 grid((M / BM) * (N / BN));            // 32*16 = 512
    dim3 block(512);

    const int ldsbytes = 2 * (BM + BN) * BK * 2;   // 131072
    (void)hipFuncSetAttribute(
        reinterpret_cast<const void*>(&awq_gemm_kernel),
        hipFuncAttributeMaxDynamicSharedMemorySize, ldsbytes);
    awq_gemm_kernel<<<grid, block, ldsbytes, stream>>>(
        x, qwp, qzp, scp, bp, outp, M, N, K);
}

// Round 7
// 392.518 us; speedup vs baseline: 1.3991x; 1.3991x over previous
//
#include <hip/hip_runtime.h>
#include <stdint.h>

// AWQ 4-bit fused dequant GEMM: out[M,N] = x[M,K] @ W[N,K]^T + bias
// fp16 MFMA 16x16x32. BM=BN=256, BK=64, 512 threads (8 waves, 2x4 of 128x64).
// Prepass: x -> fp16 in d_ws, pair-permuted + XOR-swizzle PRE-BAKED (NT stores).
// GEMM: A staged via global_load_lds_dwordx4 (linear dest = pre-swizzled src),
// B reg-staged fp16 magic dequant. 4 phases/tile {work | s_barrier | lgkmcnt(0)
// | setprio | 16 MFMA | setprio | s_barrier}; ONE vmcnt(0) per tile at P0
// (loads stay in flight across barriers). Double-buffered 128 KB LDS.

#define BM 256
#define BN 256
#define BK 64

typedef _Float16 f16x2 __attribute__((ext_vector_type(2)));
typedef _Float16 f16x8 __attribute__((ext_vector_type(8)));
typedef float f32x4 __attribute__((ext_vector_type(4)));
typedef unsigned int u32x4 __attribute__((ext_vector_type(4)));

// xh[r][kt + c'] = pairperm(x[r][kt + (c' ^ sw(r))]), sw(r)=(r&7)*8, c' 8-elem chunk
__global__ void convert_x_kernel(const float* __restrict__ x,
                                 unsigned short* __restrict__ xh,
                                 int M, int K) {
    int g = blockIdx.x * blockDim.x + threadIdx.x;
    int kc = K >> 3;                       // chunks per row
    if (g >= M * kc) return;
    int r  = g / kc;
    int cc = g - r * kc;
    int tile = cc >> 3;                    // 64-col tile
    int cpos = (cc & 7) << 3;              // dest chunk offset within tile
    int sw   = (r & 7) << 3;
    const float* p = x + (size_t)r * K + (tile << 6) + (cpos ^ sw);
    float4 f0 = *reinterpret_cast<const float4*>(p);
    float4 f1 = *reinterpret_cast<const float4*>(p + 4);
    u32x4 o;
    o.x = __builtin_bit_cast(uint32_t, __builtin_amdgcn_cvt_pkrtz(f0.x, f1.x));
    o.y = __builtin_bit_cast(uint32_t, __builtin_amdgcn_cvt_pkrtz(f0.y, f1.y));
    o.z = __builtin_bit_cast(uint32_t, __builtin_amdgcn_cvt_pkrtz(f0.z, f1.z));
    o.w = __builtin_bit_cast(uint32_t, __builtin_amdgcn_cvt_pkrtz(f0.w, f1.w));
    u32x4* dst = reinterpret_cast<u32x4*>(xh + (size_t)r * K + (tile << 6) + cpos);
    __builtin_nontemporal_store(o, dst);   // clean lines: no cross-XCD dirty bounce
}

template <bool WS>
__global__ __launch_bounds__(512, 2) void awq_gemm_kernel(
    const float* __restrict__ x,
    const unsigned short* __restrict__ xh,
    const int*   __restrict__ qw,
    const int*   __restrict__ qz,
    const float* __restrict__ sc,
    const float* __restrict__ bias,
    float*       __restrict__ out,
    int M, int N, int K)
{
    extern __shared__ __align__(16) unsigned short lds[];
    const int ASZ = BM * BK, BSZ = BN * BK;
    unsigned short* As = lds;              // [2][ASZ]
    unsigned short* Bs = lds + 2 * ASZ;    // [2][BSZ]

    const int tid  = threadIdx.x;
    const int lane = tid & 63;
    const int wave = tid >> 6;             // 0..7
    const int wr   = wave >> 2;            // 128-row half
    const int wc   = wave & 3;             // 64-col quarter
    const int lrow = lane & 15;
    const int lko  = (lane >> 4) << 3;
    const int swr  = (lrow & 7) << 3;

    const int cpx = gridDim.x >> 3;
    const int bid = (blockIdx.x & 7) * cpx + (blockIdx.x >> 3);
    const int ntn = N / BN;
    const int m0 = (bid / ntn) * BM;
    const int n0 = (bid % ntn) * BN;

    const int ngrp = K >> 7;
    const int nzw  = ngrp >> 3;
    const int kw   = K >> 3;
    const int NT   = K / BK;

    const int r_s = tid >> 1;              // 0..255 (B row; A row in !WS)
    const int kh  = tid & 1;
    const int sws = (r_s & 7) << 3;

    f32x4 acc[8][4];
    #pragma unroll
    for (int m = 0; m < 8; ++m)
        #pragma unroll
        for (int n = 0; n < 4; ++n)
            #pragma unroll
            for (int e = 0; e < 4; ++e) acc[m][n][e] = 0.f;

    uint32_t bq[4];
    float    bs_;
    uint32_t bz_;
    float4   a32[8];   // only used when !WS

    auto LOADB = [&](int kt) {
        const int4* p = reinterpret_cast<const int4*>(
            qw + (size_t)(n0 + r_s) * kw + (kt >> 3) + kh * 4);
        int4 v = *p;
        bq[0] = v.x; bq[1] = v.y; bq[2] = v.z; bq[3] = v.w;
        int grp = kt >> 7;
        bs_ = sc[(size_t)(n0 + r_s) * ngrp + grp];
        bz_ = ((uint32_t)qz[(size_t)(n0 + r_s) * nzw + (grp >> 3)] >> ((grp & 7) << 2)) & 0xF;
    };
    auto WB = [&](unsigned short* dst, int j) {
        _Float16 hs = (_Float16)bs_;
        _Float16 hz = (_Float16)(1024.0f + (float)bz_);
        f16x2 s2 = {hs, hs};
        f16x2 z2 = {hz, hz};
        const uint32_t MK = 0x000F000Fu, MG = 0x64006400u;
        uint32_t u = bq[j];
        uint32_t t0 = (u & MK) | MG;
        uint32_t t1 = ((u >> 4) & MK) | MG;
        uint32_t t2 = ((u >> 8) & MK) | MG;
        uint32_t t3 = ((u >> 12) & MK) | MG;
        f16x2 w0 = (__builtin_bit_cast(f16x2, t0) - z2) * s2;
        f16x2 w1 = (__builtin_bit_cast(f16x2, t1) - z2) * s2;
        f16x2 w2 = (__builtin_bit_cast(f16x2, t2) - z2) * s2;
        f16x2 w3 = (__builtin_bit_cast(f16x2, t3) - z2) * s2;
        uint4 o;
        o.x = __builtin_bit_cast(uint32_t, w0);
        o.y = __builtin_bit_cast(uint32_t, w1);
        o.z = __builtin_bit_cast(uint32_t, w2);
        o.w = __builtin_bit_cast(uint32_t, w3);
        int kcol = kh * 32 + 8 * j;
        *reinterpret_cast<uint4*>(&dst[r_s * BK + (kcol ^ sws)]) = o;
    };
    // A via async global->LDS: linear dest (wave base + lane*16) == pre-swizzled src
    auto GLDSA = [&](int kt, unsigned short* Aw) {
        #pragma unroll
        for (int i = 0; i < 4; ++i) {
            int row = wave * 32 + i * 8 + (lane >> 3);
            const unsigned short* g = xh + (size_t)(m0 + row) * K + kt + ((lane & 7) << 3);
            unsigned short* d = Aw + row * BK + ((lane & 7) << 3);
            __builtin_amdgcn_global_load_lds(
                (const __attribute__((address_space(1))) unsigned int*)g,
                (__attribute__((address_space(3))) unsigned int*)d, 16, 0, 0);
        }
    };
    // !WS fallback A staging (reg path)
    auto LOADA = [&](int kt) {
        const float* p = x + (size_t)(m0 + r_s) * K + kt + kh * 32;
        #pragma unroll
        for (int i = 0; i < 8; ++i)
            a32[i] = *reinterpret_cast<const float4*>(p + 4 * i);
    };
    auto WA = [&](unsigned short* dst, int c) {
        uint4 o;
        o.x = __builtin_bit_cast(uint32_t, __builtin_amdgcn_cvt_pkrtz(a32[2*c].x, a32[2*c+1].x));
        o.y = __builtin_bit_cast(uint32_t, __builtin_amdgcn_cvt_pkrtz(a32[2*c].y, a32[2*c+1].y));
        o.z = __builtin_bit_cast(uint32_t, __builtin_amdgcn_cvt_pkrtz(a32[2*c].z, a32[2*c+1].z));
        o.w = __builtin_bit_cast(uint32_t, __builtin_amdgcn_cvt_pkrtz(a32[2*c].w, a32[2*c+1].w));
        int kcol = kh * 32 + 8 * c;
        *reinterpret_cast<uint4*>(&dst[r_s * BK + (kcol ^ sws)]) = o;
    };

    f16x8 af[4], bf0[4], bf1[4];
    auto RDA = [&](const unsigned short* Ab, int mh, int kk) {
        #pragma unroll
        for (int m = 0; m < 4; ++m) {
            int arow = wr * 128 + (mh * 4 + m) * 16 + lrow;
            int idx = arow * BK + ((kk * 32 + lko) ^ swr);
            af[m] = __builtin_bit_cast(f16x8, *reinterpret_cast<const uint4*>(&Ab[idx]));
        }
    };
    auto RDB = [&](const unsigned short* Bb, f16x8* b, int kk) {
        #pragma unroll
        for (int n = 0; n < 4; ++n) {
            int brow = wc * 64 + n * 16 + lrow;
            int idx = brow * BK + ((kk * 32 + lko) ^ swr);
            b[n] = __builtin_bit_cast(f16x8, *reinterpret_cast<const uint4*>(&Bb[idx]));
        }
    };

#define PHASE(BF, MH)                                                         \
    __builtin_amdgcn_s_barrier();                                             \
    asm volatile("s_waitcnt lgkmcnt(0)" ::: "memory");                        \
    __builtin_amdgcn_sched_barrier(0);                                        \
    __builtin_amdgcn_s_setprio(1);                                            \
    _Pragma("unroll")                                                         \
    for (int m_ = 0; m_ < 4; ++m_)                                            \
        _Pragma("unroll")                                                     \
        for (int n_ = 0; n_ < 4; ++n_)                                        \
            acc[(MH)*4 + m_][n_] = __builtin_amdgcn_mfma_f32_16x16x32_f16(    \
                af[m_], BF[n_], acc[(MH)*4 + m_][n_], 0, 0, 0);               \
    __builtin_amdgcn_s_setprio(0);                                            \
    __builtin_amdgcn_s_barrier();

    // ---- prologue: stage tile 0 into buf 0
    LOADB(0);
    if constexpr (WS) {
        GLDSA(0, As);
    } else {
        LOADA(0);
    }
    asm volatile("s_waitcnt vmcnt(0)" ::: "memory");
    if constexpr (!WS) {
        #pragma unroll
        for (int c = 0; c < 4; ++c) WA(As, c);
    }
    #pragma unroll
    for (int j = 0; j < 4; ++j) WB(Bs, j);
    __syncthreads();

    for (int t = 0; t < NT; ++t) {
        const int buf = t & 1;
        const unsigned short* Ab = As + buf * ASZ;
        const unsigned short* Bb = Bs + buf * BSZ;
        unsigned short* Aw = As + (buf ^ 1) * ASZ;
        unsigned short* Bw = Bs + (buf ^ 1) * BSZ;
        const bool pf = (t + 1 < NT);

        // P0: single per-tile vmcnt drain (covers A-glds issued last tile);
        //     issue next-tile B (and !WS: A) loads; frags (mh0,kk0)
        asm volatile("s_waitcnt vmcnt(0)" ::: "memory");
        if (pf) { LOADB((t + 1) * BK); if constexpr (!WS) LOADA((t + 1) * BK); }
        RDB(Bb, bf0, 0);
        RDA(Ab, 0, 0);
        PHASE(bf0, 0)

        // P1: issue A async staging for t+1 (consumed at t+1 P0: ~3 phases away)
        RDA(Ab, 1, 0);
        if (pf) {
            if constexpr (WS) GLDSA((t + 1) * BK, Aw);
            else { WA(Aw, 0); WA(Aw, 1); }
        }
        PHASE(bf0, 1)

        // P2: B dequant slices (loads issued at P0: ~2 phases away)
        RDB(Bb, bf1, 1);
        RDA(Ab, 0, 1);
        if (pf) {
            if constexpr (!WS) { WA(Aw, 2); WA(Aw, 3); }
            WB(Bw, 0); WB(Bw, 1);
        }
        PHASE(bf1, 0)

        // P3: remaining B dequant
        RDA(Ab, 1, 1);
        if (pf) { WB(Bw, 2); WB(Bw, 3); }
        PHASE(bf1, 1)
    }
#undef PHASE

    // epilogue
    const int r4 = (lane >> 4) << 2;
    #pragma unroll
    for (int n = 0; n < 4; ++n) {
        int col = n0 + wc * 64 + n * 16 + lrow;
        float bv = bias[col];
        #pragma unroll
        for (int m = 0; m < 8; ++m) {
            size_t rbase = (size_t)(m0 + wr * 128 + m * 16 + r4) * N + col;
            #pragma unroll
            for (int e = 0; e < 4; ++e)
                __builtin_nontemporal_store(acc[m][n][e] + bv, &out[rbase + (size_t)e * N]);
        }
    }
}

extern "C" void kernel_launch(void* const* d_in, const int* in_sizes, int n_in,
                              void* d_out, int out_size, void* d_ws, size_t ws_size,
                              hipStream_t stream) {
    const float* x   = (const float*)d_in[0];
    const int*   qwp = (const int*)d_in[1];
    const int*   qzp = (const int*)d_in[2];
    const float* scp = (const float*)d_in[3];
    const float* bp  = (const float*)d_in[4];
    float* outp = (float*)d_out;

    const int N = in_sizes[4];                 // 4096 (O)
    const int K = (in_sizes[1] / N) * 8;       // 4096 (I)
    const int M = in_sizes[0] / K;             // 8192 (B)

    dim3 grid((M / BM) * (N / BN));            // 512
    dim3 block(512);
    const int ldsbytes = 2 * (BM + BN) * BK * 2;   // 131072

    const size_t need = (size_t)M * K * 2;
    if (ws_size >= need) {
        unsigned short* xh = (unsigned short*)d_ws;
        int nchunk = M * (K / 8);
        convert_x_kernel<<<dim3((nchunk + 255) / 256), dim3(256), 0, stream>>>(
            x, xh, M, K);
        (void)hipFuncSetAttribute(
            reinterpret_cast<const void*>(&awq_gemm_kernel<true>),
            hipFuncAttributeMaxDynamicSharedMemorySize, ldsbytes);
        awq_gemm_kernel<true><<<grid, block, ldsbytes, stream>>>(
            x, xh, qwp, qzp, scp, bp, outp, M, N, K);
    } else {
        (void)hipFuncSetAttribute(
            reinterpret_cast<const void*>(&awq_gemm_kernel<false>),
            hipFuncAttributeMaxDynamicSharedMemorySize, ldsbytes);
        awq_gemm_kernel<false><<<grid, block, ldsbytes, stream>>>(
            x, nullptr, qwp, qzp, scp, bp, outp, M, N, K);
    }
}

// Round 9
// 352.801 us; speedup vs baseline: 1.5567x; 1.1126x over previous
//
#include <hip/hip_runtime.h>
#include <stdint.h>

// AWQ 4-bit fused dequant GEMM: out[M,N] = x[M,K] @ W[N,K]^T + bias
// fp16 MFMA 16x16x32. BM=BN=256, BK=64, 512 threads (8 waves, 2x4 of 128x64).
// A: prepass x->fp16 (pair-permuted + XOR-swizzle pre-baked) then
//    global_load_lds_dwordx4 (zero staging VALU).
// B: PACKED int4 staged via ONE global_load_lds_dwordx4/thread (8 KB/tile),
//    dequantized at frag-read time in registers (magic-mask -> pair-permuted).
// Phases P0-P2: {work | s_barrier | lgkmcnt(0) | setprio | 16 MFMA | setprio |
// s_barrier}. P3 ends with __syncthreads(): vmcnt(0)+lgkmcnt(0) drain BEFORE
// the barrier -> cross-wave glds visibility (fixes R8 race). Loads issued at
// P0/P1 stay in flight ~3 phases. Double-buffered 80 KB LDS.

#define BM 256
#define BN 256
#define BK 64

typedef _Float16 f16x2 __attribute__((ext_vector_type(2)));
typedef _Float16 f16x8 __attribute__((ext_vector_type(8)));
typedef float f32x4 __attribute__((ext_vector_type(4)));
typedef unsigned int u32x4 __attribute__((ext_vector_type(4)));

// xh[r][tile*64 + c'] = pairperm(x[r][tile*64 + (c' ^ sw(r))]), sw(r)=(r&7)*8
__global__ void convert_x_kernel(const float* __restrict__ x,
                                 unsigned short* __restrict__ xh,
                                 int M, int K) {
    int g = blockIdx.x * blockDim.x + threadIdx.x;
    int kc = K >> 3;
    if (g >= M * kc) return;
    int r  = g / kc;
    int cc = g - r * kc;
    int tile = cc >> 3;
    int cpos = (cc & 7) << 3;
    int sw   = (r & 7) << 3;
    const float* p = x + (size_t)r * K + (tile << 6) + (cpos ^ sw);
    float4 f0 = *reinterpret_cast<const float4*>(p);
    float4 f1 = *reinterpret_cast<const float4*>(p + 4);
    u32x4 o;
    o.x = __builtin_bit_cast(uint32_t, __builtin_amdgcn_cvt_pkrtz(f0.x, f1.x));
    o.y = __builtin_bit_cast(uint32_t, __builtin_amdgcn_cvt_pkrtz(f0.y, f1.y));
    o.z = __builtin_bit_cast(uint32_t, __builtin_amdgcn_cvt_pkrtz(f0.z, f1.z));
    o.w = __builtin_bit_cast(uint32_t, __builtin_amdgcn_cvt_pkrtz(f0.w, f1.w));
    u32x4* dst = reinterpret_cast<u32x4*>(xh + (size_t)r * K + (tile << 6) + cpos);
    __builtin_nontemporal_store(o, dst);
}

template <bool WS>
__global__ __launch_bounds__(512, 2) void awq_gemm_kernel(
    const float* __restrict__ x,
    const unsigned short* __restrict__ xh,
    const int*   __restrict__ qw,
    const int*   __restrict__ qz,
    const float* __restrict__ sc,
    const float* __restrict__ bias,
    float*       __restrict__ out,
    int M, int N, int K)
{
    extern __shared__ __align__(16) unsigned short lds[];
    const int ASZ  = BM * BK;          // u16 elems per A buffer
    const int BPSZ = BN * (BK / 8);    // u32 elems per packed-B buffer
    unsigned short* As = lds;                              // [2][ASZ]
    uint32_t* Bp = reinterpret_cast<uint32_t*>(lds + 2 * ASZ);  // [2][BPSZ]

    const int tid  = threadIdx.x;
    const int lane = tid & 63;
    const int wave = tid >> 6;
    const int wr   = wave >> 2;            // 128-row half
    const int wc   = wave & 3;             // 64-col quarter
    const int lrow = lane & 15;
    const int lko  = (lane >> 4) << 3;
    const int swr  = (lrow & 7) << 3;

    const int cpx = gridDim.x >> 3;
    const int bid = (blockIdx.x & 7) * cpx + (blockIdx.x >> 3);
    const int ntn = N / BN;
    const int m0 = (bid / ntn) * BM;
    const int n0 = (bid % ntn) * BN;

    const int ngrp = K >> 7;
    const int nzw  = ngrp >> 3;
    const int kw   = K >> 3;
    const int NT   = K / BK;

    const int r_s = tid >> 1;              // !WS A staging row
    const int kh  = tid & 1;
    const int sws = (r_s & 7) << 3;

    f32x4 acc[8][4];
    #pragma unroll
    for (int m = 0; m < 8; ++m)
        #pragma unroll
        for (int n = 0; n < 4; ++n)
            #pragma unroll
            for (int e = 0; e < 4; ++e) acc[m][n][e] = 0.f;

    // per-group dequant state (per lane: rows wc*64 + n*16 + lrow)
    float    sc_pf[4];
    uint32_t zq_pf[4];
    f16x2    ss[4], zz[4];
    auto PFG = [&](int grp) {
        #pragma unroll
        for (int n = 0; n < 4; ++n) {
            int og = n0 + wc * 64 + n * 16 + lrow;
            sc_pf[n] = sc[(size_t)og * ngrp + grp];
            zq_pf[n] = (uint32_t)qz[(size_t)og * nzw + (grp >> 3)];
        }
    };
    auto SETG = [&](int grp) {
        #pragma unroll
        for (int n = 0; n < 4; ++n) {
            _Float16 s = (_Float16)sc_pf[n];
            uint32_t z = (zq_pf[n] >> ((grp & 7) << 2)) & 0xF;
            _Float16 Z = (_Float16)(float)(1024u + z);
            ss[n][0] = s; ss[n][1] = s;
            zz[n][0] = Z; zz[n][1] = Z;
        }
    };

    float4 a32[8];   // !WS only

    // B packed staging: one dwordx4 per thread = 8 KB tile (linear dest)
    auto GLDSB = [&](int kt, uint32_t* Bw) {
        int row = tid >> 1;
        const int* g = qw + (size_t)(n0 + row) * kw + (kt >> 3) + (tid & 1) * 4;
        uint32_t* d = Bw + row * 8 + (tid & 1) * 4;
        __builtin_amdgcn_global_load_lds(
            (const __attribute__((address_space(1))) unsigned int*)g,
            (__attribute__((address_space(3))) unsigned int*)d, 16, 0, 0);
    };
    // A async staging (WS): linear dest == pre-swizzled source
    auto GLDSA = [&](int kt, unsigned short* Aw) {
        #pragma unroll
        for (int i = 0; i < 4; ++i) {
            int row = wave * 32 + i * 8 + (lane >> 3);
            const unsigned short* g = xh + (size_t)(m0 + row) * K + kt + ((lane & 7) << 3);
            unsigned short* d = Aw + row * BK + ((lane & 7) << 3);
            __builtin_amdgcn_global_load_lds(
                (const __attribute__((address_space(1))) unsigned int*)g,
                (__attribute__((address_space(3))) unsigned int*)d, 16, 0, 0);
        }
    };
    // !WS fallback A staging
    auto LOADA = [&](int kt) {
        const float* p = x + (size_t)(m0 + r_s) * K + kt + kh * 32;
        #pragma unroll
        for (int i = 0; i < 8; ++i)
            a32[i] = *reinterpret_cast<const float4*>(p + 4 * i);
    };
    auto WA = [&](unsigned short* dst, int c) {
        uint4 o;
        o.x = __builtin_bit_cast(uint32_t, __builtin_amdgcn_cvt_pkrtz(a32[2*c].x, a32[2*c+1].x));
        o.y = __builtin_bit_cast(uint32_t, __builtin_amdgcn_cvt_pkrtz(a32[2*c].y, a32[2*c+1].y));
        o.z = __builtin_bit_cast(uint32_t, __builtin_amdgcn_cvt_pkrtz(a32[2*c].z, a32[2*c+1].z));
        o.w = __builtin_bit_cast(uint32_t, __builtin_amdgcn_cvt_pkrtz(a32[2*c].w, a32[2*c+1].w));
        int kcol = kh * 32 + 8 * c;
        *reinterpret_cast<uint4*>(&dst[r_s * BK + (kcol ^ sws)]) = o;
    };

    f16x8 af[4], bfA[4], bfB[4];
    auto RDA = [&](const unsigned short* Ab, int mh, int kk) {
        #pragma unroll
        for (int m = 0; m < 4; ++m) {
            int arow = wr * 128 + (mh * 4 + m) * 16 + lrow;
            int idx = arow * BK + ((kk * 32 + lko) ^ swr);
            af[m] = __builtin_bit_cast(f16x8, *reinterpret_cast<const uint4*>(&Ab[idx]));
        }
    };
    // read packed dword + dequant -> pair-permuted f16x8 frag
    auto DEQB = [&](const uint32_t* Bpb, f16x8* b, int kk) {
        const int dcol = kk * 4 + (lane >> 4);
        const uint32_t MK = 0x000F000Fu, MG = 0x64006400u;
        #pragma unroll
        for (int n = 0; n < 4; ++n) {
            int brow = wc * 64 + n * 16 + lrow;
            uint32_t u = Bpb[brow * 8 + dcol];
            uint32_t p0 = (u & MK) | MG;
            uint32_t p1 = ((u >> 4) & MK) | MG;
            uint32_t p2 = ((u >> 8) & MK) | MG;
            uint32_t p3 = ((u >> 12) & MK) | MG;
            u32x4 o;
            o.x = __builtin_bit_cast(uint32_t, (__builtin_bit_cast(f16x2, p0) - zz[n]) * ss[n]);
            o.y = __builtin_bit_cast(uint32_t, (__builtin_bit_cast(f16x2, p1) - zz[n]) * ss[n]);
            o.z = __builtin_bit_cast(uint32_t, (__builtin_bit_cast(f16x2, p2) - zz[n]) * ss[n]);
            o.w = __builtin_bit_cast(uint32_t, (__builtin_bit_cast(f16x2, p3) - zz[n]) * ss[n]);
            b[n] = __builtin_bit_cast(f16x8, o);
        }
    };

#define PHASE(BF, MH)                                                         \
    __builtin_amdgcn_s_barrier();                                             \
    asm volatile("s_waitcnt lgkmcnt(0)" ::: "memory");                        \
    __builtin_amdgcn_sched_barrier(0);                                        \
    __builtin_amdgcn_s_setprio(1);                                            \
    _Pragma("unroll")                                                         \
    for (int m_ = 0; m_ < 4; ++m_)                                            \
        _Pragma("unroll")                                                     \
        for (int n_ = 0; n_ < 4; ++n_)                                        \
            acc[(MH)*4 + m_][n_] = __builtin_amdgcn_mfma_f32_16x16x32_f16(    \
                af[m_], BF[n_], acc[(MH)*4 + m_][n_], 0, 0, 0);               \
    __builtin_amdgcn_s_setprio(0);                                            \
    __builtin_amdgcn_s_barrier();

// tile-final phase: trailing __syncthreads() = vmcnt(0)+lgkmcnt(0) drain THEN
// barrier -> all waves' async glds for tile t+1 are visible to all waves.
#define PHASE_END(BF, MH)                                                     \
    __builtin_amdgcn_s_barrier();                                             \
    asm volatile("s_waitcnt lgkmcnt(0)" ::: "memory");                        \
    __builtin_amdgcn_sched_barrier(0);                                        \
    __builtin_amdgcn_s_setprio(1);                                            \
    _Pragma("unroll")                                                         \
    for (int m_ = 0; m_ < 4; ++m_)                                            \
        _Pragma("unroll")                                                     \
        for (int n_ = 0; n_ < 4; ++n_)                                        \
            acc[(MH)*4 + m_][n_] = __builtin_amdgcn_mfma_f32_16x16x32_f16(    \
                af[m_], BF[n_], acc[(MH)*4 + m_][n_], 0, 0, 0);               \
    __builtin_amdgcn_s_setprio(0);                                            \
    __syncthreads();

    // ---- prologue: stage tile 0 into buf 0 (drain-then-barrier)
    PFG(0);
    GLDSB(0, Bp);
    if constexpr (WS) {
        GLDSA(0, As);
    } else {
        LOADA(0);
    }
    asm volatile("s_waitcnt vmcnt(0)" ::: "memory");
    if constexpr (!WS) {
        #pragma unroll
        for (int c = 0; c < 4; ++c) WA(As, c);
    }
    SETG(0);
    __syncthreads();

    for (int t = 0; t < NT; ++t) {
        const int buf = t & 1;
        const unsigned short* Ab = As + buf * ASZ;
        const uint32_t* Bpb = Bp + buf * BPSZ;
        unsigned short* Aw = As + (buf ^ 1) * ASZ;
        uint32_t* Bw = Bp + (buf ^ 1) * BPSZ;
        const bool pf = (t + 1 < NT);
        const int grp = t >> 1;

        // P0: new-group SETG (even t); issue B glds + group prefetch (odd t);
        //     dequant kk0 frags; read A(mh0,kk0)
        if (t && !(t & 1)) SETG(grp);
        if (pf) {
            GLDSB((t + 1) * BK, Bw);
            if constexpr (!WS) LOADA((t + 1) * BK);
            if ((t & 1) && grp + 1 < ngrp) PFG(grp + 1);
        }
        DEQB(Bpb, bfA, 0);
        RDA(Ab, 0, 0);
        PHASE(bfA, 0)

        // P1: read A(mh1,kk0); issue A staging for t+1
        RDA(Ab, 1, 0);
        if (pf) {
            if constexpr (WS) GLDSA((t + 1) * BK, Aw);
            else { WA(Aw, 0); WA(Aw, 1); }
        }
        PHASE(bfA, 1)

        // P2: dequant kk1 frags; read A(mh0,kk1)
        DEQB(Bpb, bfB, 1);
        RDA(Ab, 0, 1);
        if constexpr (!WS) { if (pf) { WA(Aw, 2); WA(Aw, 3); } }
        PHASE(bfB, 0)

        // P3: read A(mh1,kk1); tile-end drain+barrier
        RDA(Ab, 1, 1);
        PHASE_END(bfB, 1)
    }
#undef PHASE
#undef PHASE_END

    // epilogue
    const int r4 = (lane >> 4) << 2;
    #pragma unroll
    for (int n = 0; n < 4; ++n) {
        int col = n0 + wc * 64 + n * 16 + lrow;
        float bv = bias[col];
        #pragma unroll
        for (int m = 0; m < 8; ++m) {
            size_t rbase = (size_t)(m0 + wr * 128 + m * 16 + r4) * N + col;
            #pragma unroll
            for (int e = 0; e < 4; ++e)
                __builtin_nontemporal_store(acc[m][n][e] + bv, &out[rbase + (size_t)e * N]);
        }
    }
}

extern "C" void kernel_launch(void* const* d_in, const int* in_sizes, int n_in,
                              void* d_out, int out_size, void* d_ws, size_t ws_size,
                              hipStream_t stream) {
    const float* x   = (const float*)d_in[0];
    const int*   qwp = (const int*)d_in[1];
    const int*   qzp = (const int*)d_in[2];
    const float* scp = (const float*)d_in[3];
    const float* bp  = (const float*)d_in[4];
    float* outp = (float*)d_out;

    const int N = in_sizes[4];                 // 4096 (O)
    const int K = (in_sizes[1] / N) * 8;       // 4096 (I)
    const int M = in_sizes[0] / K;             // 8192 (B)

    dim3 grid((M / BM) * (N / BN));            // 512
    dim3 block(512);
    // LDS: A 2*256*64*2 = 64 KB + Bp 2*256*8*4 = 16 KB
    const int ldsbytes = 2 * BM * BK * 2 + 2 * BN * (BK / 8) * 4;

    const size_t need = (size_t)M * K * 2;
    if (ws_size >= need) {
        unsigned short* xh = (unsigned short*)d_ws;
        int nchunk = M * (K / 8);
        convert_x_kernel<<<dim3((nchunk + 255) / 256), dim3(256), 0, stream>>>(
            x, xh, M, K);
        (void)hipFuncSetAttribute(
            reinterpret_cast<const void*>(&awq_gemm_kernel<true>),
            hipFuncAttributeMaxDynamicSharedMemorySize, ldsbytes);
        awq_gemm_kernel<true><<<grid, block, ldsbytes, stream>>>(
            x, xh, qwp, qzp, scp, bp, outp, M, N, K);
    } else {
        (void)hipFuncSetAttribute(
            reinterpret_cast<const void*>(&awq_gemm_kernel<false>),
            hipFuncAttributeMaxDynamicSharedMemorySize, ldsbytes);
        awq_gemm_kernel<false><<<grid, block, ldsbytes, stream>>>(
            x, nullptr, qwp, qzp, scp, bp, outp, M, N, K);
    }
}

// Round 10
// 336.855 us; speedup vs baseline: 1.6303x; 1.0473x over previous
//
#include <hip/hip_runtime.h>
#include <stdint.h>

// AWQ 4-bit fused dequant GEMM: out[M,N] = x[M,K] @ W[N,K]^T + bias
// fp16 MFMA 16x16x32. BM=BN=256, BK=64, 512 threads (8 waves, 2x4 of 128x64).
// A: prepass x->fp16 (pair-permuted + XOR-swizzle pre-baked) -> glds dwordx4.
// B: packed int4 via ONE glds dwordx4/thread; dequant at frag-read (magic-mask).
// WS path: ONE __syncthreads() per K-tile (drain-then-barrier). No other
// fences: LDS reads are from the stable buffer, glds writes go to buf^1, so
// mid-tile barriers protect nothing; compiler-inserted waitcnts handle frag
// deps; wave drift lets DEQB VALU overlap other waves' MFMA (m114).

#define BM 256
#define BN 256
#define BK 64

typedef _Float16 f16x2 __attribute__((ext_vector_type(2)));
typedef _Float16 f16x8 __attribute__((ext_vector_type(8)));
typedef float f32x4 __attribute__((ext_vector_type(4)));
typedef unsigned int u32x4 __attribute__((ext_vector_type(4)));

// xh[r][tile*64 + c'] = pairperm(x[r][tile*64 + (c' ^ sw(r))]), sw(r)=(r&7)*8
__global__ void convert_x_kernel(const float* __restrict__ x,
                                 unsigned short* __restrict__ xh,
                                 int M, int K) {
    int g = blockIdx.x * blockDim.x + threadIdx.x;
    int kc = K >> 3;
    if (g >= M * kc) return;
    int r  = g / kc;
    int cc = g - r * kc;
    int tile = cc >> 3;
    int cpos = (cc & 7) << 3;
    int sw   = (r & 7) << 3;
    const float* p = x + (size_t)r * K + (tile << 6) + (cpos ^ sw);
    float4 f0 = *reinterpret_cast<const float4*>(p);
    float4 f1 = *reinterpret_cast<const float4*>(p + 4);
    u32x4 o;
    o.x = __builtin_bit_cast(uint32_t, __builtin_amdgcn_cvt_pkrtz(f0.x, f1.x));
    o.y = __builtin_bit_cast(uint32_t, __builtin_amdgcn_cvt_pkrtz(f0.y, f1.y));
    o.z = __builtin_bit_cast(uint32_t, __builtin_amdgcn_cvt_pkrtz(f0.z, f1.z));
    o.w = __builtin_bit_cast(uint32_t, __builtin_amdgcn_cvt_pkrtz(f0.w, f1.w));
    u32x4* dst = reinterpret_cast<u32x4*>(xh + (size_t)r * K + (tile << 6) + cpos);
    __builtin_nontemporal_store(o, dst);
}

template <bool WS>
__global__ __launch_bounds__(512, 2) void awq_gemm_kernel(
    const float* __restrict__ x,
    const unsigned short* __restrict__ xh,
    const int*   __restrict__ qw,
    const int*   __restrict__ qz,
    const float* __restrict__ sc,
    const float* __restrict__ bias,
    float*       __restrict__ out,
    int M, int N, int K)
{
    extern __shared__ __align__(16) unsigned short lds[];
    const int ASZ  = BM * BK;          // u16 per A buffer
    const int BPSZ = BN * (BK / 8);    // u32 per packed-B buffer
    unsigned short* As = lds;                              // [2][ASZ]
    uint32_t* Bp = reinterpret_cast<uint32_t*>(lds + 2 * ASZ);  // [2][BPSZ]

    const int tid  = threadIdx.x;
    const int lane = tid & 63;
    const int wave = tid >> 6;
    const int wr   = wave >> 2;            // 128-row half
    const int wc   = wave & 3;             // 64-col quarter
    const int lrow = lane & 15;
    const int lko  = (lane >> 4) << 3;
    const int swr  = (lrow & 7) << 3;

    const int cpx = gridDim.x >> 3;
    const int bid = (blockIdx.x & 7) * cpx + (blockIdx.x >> 3);
    const int ntn = N / BN;
    const int m0 = (bid / ntn) * BM;
    const int n0 = (bid % ntn) * BN;

    const int ngrp = K >> 7;
    const int nzw  = ngrp >> 3;
    const int kw   = K >> 3;
    const int NT   = K / BK;

    const int r_s = tid >> 1;              // !WS A staging row
    const int kh  = tid & 1;
    const int sws = (r_s & 7) << 3;

    f32x4 acc[8][4];
    #pragma unroll
    for (int m = 0; m < 8; ++m)
        #pragma unroll
        for (int n = 0; n < 4; ++n)
            #pragma unroll
            for (int e = 0; e < 4; ++e) acc[m][n][e] = 0.f;

    // per-group dequant state (per lane: rows wc*64 + n*16 + lrow)
    float    sc_pf[4];
    uint32_t zq_pf[4];
    f16x2    ss[4], zz[4];
    auto PFG = [&](int grp) {
        #pragma unroll
        for (int n = 0; n < 4; ++n) {
            int og = n0 + wc * 64 + n * 16 + lrow;
            sc_pf[n] = sc[(size_t)og * ngrp + grp];
            zq_pf[n] = (uint32_t)qz[(size_t)og * nzw + (grp >> 3)];
        }
    };
    auto SETG = [&](int grp) {
        #pragma unroll
        for (int n = 0; n < 4; ++n) {
            _Float16 s = (_Float16)sc_pf[n];
            uint32_t z = (zq_pf[n] >> ((grp & 7) << 2)) & 0xF;
            _Float16 Z = (_Float16)(float)(1024u + z);
            ss[n][0] = s; ss[n][1] = s;
            zz[n][0] = Z; zz[n][1] = Z;
        }
    };

    float4 a32[8];   // !WS only

    // B packed staging: one dwordx4 per thread = 8 KB tile (linear dest)
    auto GLDSB = [&](int kt, uint32_t* Bw) {
        int row = tid >> 1;
        const int* g = qw + (size_t)(n0 + row) * kw + (kt >> 3) + (tid & 1) * 4;
        uint32_t* d = Bw + row * 8 + (tid & 1) * 4;
        __builtin_amdgcn_global_load_lds(
            (const __attribute__((address_space(1))) unsigned int*)g,
            (__attribute__((address_space(3))) unsigned int*)d, 16, 0, 0);
    };
    // A async staging (WS): linear dest == pre-swizzled source
    auto GLDSA = [&](int kt, unsigned short* Aw) {
        #pragma unroll
        for (int i = 0; i < 4; ++i) {
            int row = wave * 32 + i * 8 + (lane >> 3);
            const unsigned short* g = xh + (size_t)(m0 + row) * K + kt + ((lane & 7) << 3);
            unsigned short* d = Aw + row * BK + ((lane & 7) << 3);
            __builtin_amdgcn_global_load_lds(
                (const __attribute__((address_space(1))) unsigned int*)g,
                (__attribute__((address_space(3))) unsigned int*)d, 16, 0, 0);
        }
    };
    // !WS fallback A staging
    auto LOADA = [&](int kt) {
        const float* p = x + (size_t)(m0 + r_s) * K + kt + kh * 32;
        #pragma unroll
        for (int i = 0; i < 8; ++i)
            a32[i] = *reinterpret_cast<const float4*>(p + 4 * i);
    };
    auto WA = [&](unsigned short* dst, int c) {
        uint4 o;
        o.x = __builtin_bit_cast(uint32_t, __builtin_amdgcn_cvt_pkrtz(a32[2*c].x, a32[2*c+1].x));
        o.y = __builtin_bit_cast(uint32_t, __builtin_amdgcn_cvt_pkrtz(a32[2*c].y, a32[2*c+1].y));
        o.z = __builtin_bit_cast(uint32_t, __builtin_amdgcn_cvt_pkrtz(a32[2*c].z, a32[2*c+1].z));
        o.w = __builtin_bit_cast(uint32_t, __builtin_amdgcn_cvt_pkrtz(a32[2*c].w, a32[2*c+1].w));
        int kcol = kh * 32 + 8 * c;
        *reinterpret_cast<uint4*>(&dst[r_s * BK + (kcol ^ sws)]) = o;
    };

    f16x8 af[4], bfA[4], bfB[4];
    auto RDA = [&](const unsigned short* Ab, int mh, int kk) {
        #pragma unroll
        for (int m = 0; m < 4; ++m) {
            int arow = wr * 128 + (mh * 4 + m) * 16 + lrow;
            int idx = arow * BK + ((kk * 32 + lko) ^ swr);
            af[m] = __builtin_bit_cast(f16x8, *reinterpret_cast<const uint4*>(&Ab[idx]));
        }
    };
    // read packed dword + dequant -> pair-permuted f16x8 frag
    auto DEQB = [&](const uint32_t* Bpb, f16x8* b, int kk) {
        const int dcol = kk * 4 + (lane >> 4);
        const uint32_t MK = 0x000F000Fu, MG = 0x64006400u;
        #pragma unroll
        for (int n = 0; n < 4; ++n) {
            int brow = wc * 64 + n * 16 + lrow;
            uint32_t u = Bpb[brow * 8 + dcol];
            uint32_t p0 = (u & MK) | MG;
            uint32_t p1 = ((u >> 4) & MK) | MG;
            uint32_t p2 = ((u >> 8) & MK) | MG;
            uint32_t p3 = ((u >> 12) & MK) | MG;
            u32x4 o;
            o.x = __builtin_bit_cast(uint32_t, (__builtin_bit_cast(f16x2, p0) - zz[n]) * ss[n]);
            o.y = __builtin_bit_cast(uint32_t, (__builtin_bit_cast(f16x2, p1) - zz[n]) * ss[n]);
            o.z = __builtin_bit_cast(uint32_t, (__builtin_bit_cast(f16x2, p2) - zz[n]) * ss[n]);
            o.w = __builtin_bit_cast(uint32_t, (__builtin_bit_cast(f16x2, p3) - zz[n]) * ss[n]);
            b[n] = __builtin_bit_cast(f16x8, o);
        }
    };
    auto MFMAQ = [&](f16x8* bf, int mh) {
        #pragma unroll
        for (int m_ = 0; m_ < 4; ++m_)
            #pragma unroll
            for (int n_ = 0; n_ < 4; ++n_)
                acc[mh * 4 + m_][n_] = __builtin_amdgcn_mfma_f32_16x16x32_f16(
                    af[m_], bf[n_], acc[mh * 4 + m_][n_], 0, 0, 0);
    };

    // ---- prologue: stage tile 0 into buf 0 (drain-then-barrier)
    PFG(0);
    GLDSB(0, Bp);
    if constexpr (WS) {
        GLDSA(0, As);
    } else {
        LOADA(0);
    }
    asm volatile("s_waitcnt vmcnt(0)" ::: "memory");
    if constexpr (!WS) {
        #pragma unroll
        for (int c = 0; c < 4; ++c) WA(As, c);
    }
    SETG(0);
    __syncthreads();

    for (int t = 0; t < NT; ++t) {
        const int buf = t & 1;
        const unsigned short* Ab = As + buf * ASZ;
        const uint32_t* Bpb = Bp + buf * BPSZ;
        unsigned short* Aw = As + (buf ^ 1) * ASZ;
        uint32_t* Bw = Bp + (buf ^ 1) * BPSZ;
        const bool pf = (t + 1 < NT);
        const int grp = t >> 1;

        // group-state update + next-group prefetch
        if (t && !(t & 1)) SETG(grp);
        if (pf) {
            GLDSB((t + 1) * BK, Bw);
            if constexpr (WS) GLDSA((t + 1) * BK, Aw);
            else LOADA((t + 1) * BK);
            if ((t & 1) && grp + 1 < ngrp) PFG(grp + 1);
        }

        // compute: 4 quadrants, plain code — compiler schedules, waves drift
        DEQB(Bpb, bfA, 0);
        RDA(Ab, 0, 0);
        MFMAQ(bfA, 0);
        RDA(Ab, 1, 0);
        MFMAQ(bfA, 1);
        DEQB(Bpb, bfB, 1);
        RDA(Ab, 0, 1);
        MFMAQ(bfB, 0);
        RDA(Ab, 1, 1);
        MFMAQ(bfB, 1);

        if constexpr (!WS) {
            if (pf) { WA(Aw, 0); WA(Aw, 1); WA(Aw, 2); WA(Aw, 3); }
        }
        // ONE sync per tile: drains vmcnt (glds visibility) + lgkm, then barrier
        __syncthreads();
    }

    // epilogue
    const int r4 = (lane >> 4) << 2;
    #pragma unroll
    for (int n = 0; n < 4; ++n) {
        int col = n0 + wc * 64 + n * 16 + lrow;
        float bv = bias[col];
        #pragma unroll
        for (int m = 0; m < 8; ++m) {
            size_t rbase = (size_t)(m0 + wr * 128 + m * 16 + r4) * N + col;
            #pragma unroll
            for (int e = 0; e < 4; ++e)
                __builtin_nontemporal_store(acc[m][n][e] + bv, &out[rbase + (size_t)e * N]);
        }
    }
}

extern "C" void kernel_launch(void* const* d_in, const int* in_sizes, int n_in,
                              void* d_out, int out_size, void* d_ws, size_t ws_size,
                              hipStream_t stream) {
    const float* x   = (const float*)d_in[0];
    const int*   qwp = (const int*)d_in[1];
    const int*   qzp = (const int*)d_in[2];
    const float* scp = (const float*)d_in[3];
    const float* bp  = (const float*)d_in[4];
    float* outp = (float*)d_out;

    const int N = in_sizes[4];                 // 4096 (O)
    const int K = (in_sizes[1] / N) * 8;       // 4096 (I)
    const int M = in_sizes[0] / K;             // 8192 (B)

    dim3 grid((M / BM) * (N / BN));            // 512
    dim3 block(512);
    // LDS: A 2*256*64*2 = 64 KB + Bp 2*256*8*4 = 16 KB
    const int ldsbytes = 2 * BM * BK * 2 + 2 * BN * (BK / 8) * 4;

    const size_t need = (size_t)M * K * 2;
    if (ws_size >= need) {
        unsigned short* xh = (unsigned short*)d_ws;
        int nchunk = M * (K / 8);
        convert_x_kernel<<<dim3((nchunk + 255) / 256), dim3(256), 0, stream>>>(
            x, xh, M, K);
        (void)hipFuncSetAttribute(
            reinterpret_cast<const void*>(&awq_gemm_kernel<true>),
            hipFuncAttributeMaxDynamicSharedMemorySize, ldsbytes);
        awq_gemm_kernel<true><<<grid, block, ldsbytes, stream>>>(
            x, xh, qwp, qzp, scp, bp, outp, M, N, K);
    } else {
        (void)hipFuncSetAttribute(
            reinterpret_cast<const void*>(&awq_gemm_kernel<false>),
            hipFuncAttributeMaxDynamicSharedMemorySize, ldsbytes);
        awq_gemm_kernel<false><<<grid, block, ldsbytes, stream>>>(
            x, nullptr, qwp, qzp, scp, bp, outp, M, N, K);
    }
}

// Round 11
// 332.619 us; speedup vs baseline: 1.6511x; 1.0127x over previous
//
#include <hip/hip_runtime.h>
#include <stdint.h>

// AWQ 4-bit fused dequant GEMM: out[M,N] = x[M,K] @ W[N,K]^T + bias
// fp16 MFMA 16x16x32. BM=BN=256, BK=64, 512 threads (8 waves, 2x4 of 128x64).
// A: prepass x->fp16 (pair-permuted + XOR-swizzle pre-baked) -> glds dwordx4.
// B: packed int4 via ONE glds dwordx4/thread; dequant at frag-read (magic-mask).
// WS path: TRIPLE-buffered LDS; during tile t issue glds for t+2; tile end =
// s_waitcnt vmcnt(5) (5 = this tile's glds) + raw s_barrier. FIFO: <=5
// outstanding (newest, t+2's) => t+1's loads done => visible after barrier.
// NO vmcnt(0) drain anywhere in the loop (T4 counted-vmcnt, m218).

#define BM 256
#define BN 256
#define BK 64

typedef _Float16 f16x2 __attribute__((ext_vector_type(2)));
typedef _Float16 f16x8 __attribute__((ext_vector_type(8)));
typedef float f32x4 __attribute__((ext_vector_type(4)));
typedef unsigned int u32x4 __attribute__((ext_vector_type(4)));

// xh[r][tile*64 + c'] = pairperm(x[r][tile*64 + (c' ^ sw(r))]), sw(r)=(r&7)*8
__global__ void convert_x_kernel(const float* __restrict__ x,
                                 unsigned short* __restrict__ xh,
                                 int M, int K) {
    int g = blockIdx.x * blockDim.x + threadIdx.x;
    int kc = K >> 3;
    if (g >= M * kc) return;
    int r  = g / kc;
    int cc = g - r * kc;
    int tile = cc >> 3;
    int cpos = (cc & 7) << 3;
    int sw   = (r & 7) << 3;
    const float* p = x + (size_t)r * K + (tile << 6) + (cpos ^ sw);
    float4 f0 = *reinterpret_cast<const float4*>(p);
    float4 f1 = *reinterpret_cast<const float4*>(p + 4);
    u32x4 o;
    o.x = __builtin_bit_cast(uint32_t, __builtin_amdgcn_cvt_pkrtz(f0.x, f1.x));
    o.y = __builtin_bit_cast(uint32_t, __builtin_amdgcn_cvt_pkrtz(f0.y, f1.y));
    o.z = __builtin_bit_cast(uint32_t, __builtin_amdgcn_cvt_pkrtz(f0.z, f1.z));
    o.w = __builtin_bit_cast(uint32_t, __builtin_amdgcn_cvt_pkrtz(f0.w, f1.w));
    u32x4* dst = reinterpret_cast<u32x4*>(xh + (size_t)r * K + (tile << 6) + cpos);
    __builtin_nontemporal_store(o, dst);
}

template <bool WS>
__global__ __launch_bounds__(512, 2) void awq_gemm_kernel(
    const float* __restrict__ x,
    const unsigned short* __restrict__ xh,
    const int*   __restrict__ qw,
    const int*   __restrict__ qz,
    const float* __restrict__ sc,
    const float* __restrict__ bias,
    float*       __restrict__ out,
    int M, int N, int K)
{
    extern __shared__ __align__(16) unsigned short lds[];
    const int ASZ  = BM * BK;          // u16 per A buffer
    const int BPSZ = BN * (BK / 8);    // u32 per packed-B buffer
    const int NBUF = WS ? 3 : 2;
    unsigned short* As = lds;                                   // [NBUF][ASZ]
    uint32_t* Bp = reinterpret_cast<uint32_t*>(lds + NBUF * ASZ); // [NBUF][BPSZ]

    const int tid  = threadIdx.x;
    const int lane = tid & 63;
    const int wave = tid >> 6;
    const int wr   = wave >> 2;            // 128-row half
    const int wc   = wave & 3;             // 64-col quarter
    const int lrow = lane & 15;
    const int lko  = (lane >> 4) << 3;
    const int swr  = (lrow & 7) << 3;

    const int cpx = gridDim.x >> 3;
    const int bid = (blockIdx.x & 7) * cpx + (blockIdx.x >> 3);
    const int ntn = N / BN;
    const int m0 = (bid / ntn) * BM;
    const int n0 = (bid % ntn) * BN;

    const int ngrp = K >> 7;
    const int nzw  = ngrp >> 3;
    const int kw   = K >> 3;
    const int NT   = K / BK;

    const int r_s = tid >> 1;              // !WS A staging row
    const int kh  = tid & 1;
    const int sws = (r_s & 7) << 3;

    f32x4 acc[8][4];
    #pragma unroll
    for (int m = 0; m < 8; ++m)
        #pragma unroll
        for (int n = 0; n < 4; ++n)
            #pragma unroll
            for (int e = 0; e < 4; ++e) acc[m][n][e] = 0.f;

    // per-group dequant state (per lane: rows wc*64 + n*16 + lrow)
    float    sc_pf[4];
    uint32_t zq_pf[4];
    f16x2    ss[4], zz[4];
    auto PFG = [&](int grp) {
        #pragma unroll
        for (int n = 0; n < 4; ++n) {
            int og = n0 + wc * 64 + n * 16 + lrow;
            sc_pf[n] = sc[(size_t)og * ngrp + grp];
            zq_pf[n] = (uint32_t)qz[(size_t)og * nzw + (grp >> 3)];
        }
    };
    auto SETG = [&](int grp) {
        #pragma unroll
        for (int n = 0; n < 4; ++n) {
            _Float16 s = (_Float16)sc_pf[n];
            uint32_t z = (zq_pf[n] >> ((grp & 7) << 2)) & 0xF;
            _Float16 Z = (_Float16)(float)(1024u + z);
            ss[n][0] = s; ss[n][1] = s;
            zz[n][0] = Z; zz[n][1] = Z;
        }
    };

    float4 a32[8];   // !WS only

    // B packed staging: one dwordx4 per thread = 8 KB tile (1 vmem inst/wave)
    auto GLDSB = [&](int kt, uint32_t* Bw) {
        int row = tid >> 1;
        const int* g = qw + (size_t)(n0 + row) * kw + (kt >> 3) + (tid & 1) * 4;
        uint32_t* d = Bw + row * 8 + (tid & 1) * 4;
        __builtin_amdgcn_global_load_lds(
            (const __attribute__((address_space(1))) unsigned int*)g,
            (__attribute__((address_space(3))) unsigned int*)d, 16, 0, 0);
    };
    // A async staging (WS): linear dest == pre-swizzled source (4 vmem inst/wave)
    auto GLDSA = [&](int kt, unsigned short* Aw) {
        #pragma unroll
        for (int i = 0; i < 4; ++i) {
            int row = wave * 32 + i * 8 + (lane >> 3);
            const unsigned short* g = xh + (size_t)(m0 + row) * K + kt + ((lane & 7) << 3);
            unsigned short* d = Aw + row * BK + ((lane & 7) << 3);
            __builtin_amdgcn_global_load_lds(
                (const __attribute__((address_space(1))) unsigned int*)g,
                (__attribute__((address_space(3))) unsigned int*)d, 16, 0, 0);
        }
    };
    // !WS fallback A staging
    auto LOADA = [&](int kt) {
        const float* p = x + (size_t)(m0 + r_s) * K + kt + kh * 32;
        #pragma unroll
        for (int i = 0; i < 8; ++i)
            a32[i] = *reinterpret_cast<const float4*>(p + 4 * i);
    };
    auto WA = [&](unsigned short* dst, int c) {
        uint4 o;
        o.x = __builtin_bit_cast(uint32_t, __builtin_amdgcn_cvt_pkrtz(a32[2*c].x, a32[2*c+1].x));
        o.y = __builtin_bit_cast(uint32_t, __builtin_amdgcn_cvt_pkrtz(a32[2*c].y, a32[2*c+1].y));
        o.z = __builtin_bit_cast(uint32_t, __builtin_amdgcn_cvt_pkrtz(a32[2*c].z, a32[2*c+1].z));
        o.w = __builtin_bit_cast(uint32_t, __builtin_amdgcn_cvt_pkrtz(a32[2*c].w, a32[2*c+1].w));
        int kcol = kh * 32 + 8 * c;
        *reinterpret_cast<uint4*>(&dst[r_s * BK + (kcol ^ sws)]) = o;
    };

    f16x8 af[4], bfA[4], bfB[4];
    auto RDA = [&](const unsigned short* Ab, int mh, int kk) {
        #pragma unroll
        for (int m = 0; m < 4; ++m) {
            int arow = wr * 128 + (mh * 4 + m) * 16 + lrow;
            int idx = arow * BK + ((kk * 32 + lko) ^ swr);
            af[m] = __builtin_bit_cast(f16x8, *reinterpret_cast<const uint4*>(&Ab[idx]));
        }
    };
    // read packed dword + dequant -> pair-permuted f16x8 frag
    auto DEQB = [&](const uint32_t* Bpb, f16x8* b, int kk) {
        const int dcol = kk * 4 + (lane >> 4);
        const uint32_t MK = 0x000F000Fu, MG = 0x64006400u;
        #pragma unroll
        for (int n = 0; n < 4; ++n) {
            int brow = wc * 64 + n * 16 + lrow;
            uint32_t u = Bpb[brow * 8 + dcol];
            uint32_t p0 = (u & MK) | MG;
            uint32_t p1 = ((u >> 4) & MK) | MG;
            uint32_t p2 = ((u >> 8) & MK) | MG;
            uint32_t p3 = ((u >> 12) & MK) | MG;
            u32x4 o;
            o.x = __builtin_bit_cast(uint32_t, (__builtin_bit_cast(f16x2, p0) - zz[n]) * ss[n]);
            o.y = __builtin_bit_cast(uint32_t, (__builtin_bit_cast(f16x2, p1) - zz[n]) * ss[n]);
            o.z = __builtin_bit_cast(uint32_t, (__builtin_bit_cast(f16x2, p2) - zz[n]) * ss[n]);
            o.w = __builtin_bit_cast(uint32_t, (__builtin_bit_cast(f16x2, p3) - zz[n]) * ss[n]);
            b[n] = __builtin_bit_cast(f16x8, o);
        }
    };
    auto MFMAQ = [&](f16x8* bf, int mh) {
        #pragma unroll
        for (int m_ = 0; m_ < 4; ++m_)
            #pragma unroll
            for (int n_ = 0; n_ < 4; ++n_)
                acc[mh * 4 + m_][n_] = __builtin_amdgcn_mfma_f32_16x16x32_f16(
                    af[m_], bf[n_], acc[mh * 4 + m_][n_], 0, 0, 0);
    };

    // ---- prologue
    PFG(0);
    if constexpr (WS) {
        // stage tiles 0 and 1 into buf0/buf1, full drain once, barrier
        GLDSB(0, Bp);
        GLDSA(0, As);
        if (NT > 1) { GLDSB(BK, Bp + BPSZ); GLDSA(BK, As + ASZ); }
        asm volatile("s_waitcnt vmcnt(0)" ::: "memory");
        SETG(0);
        __syncthreads();
    } else {
        GLDSB(0, Bp);
        LOADA(0);
        asm volatile("s_waitcnt vmcnt(0)" ::: "memory");
        #pragma unroll
        for (int c = 0; c < 4; ++c) WA(As, c);
        SETG(0);
        __syncthreads();
    }

    for (int t = 0; t < NT; ++t) {
        const int grp = t >> 1;
        if (t && !(t & 1)) SETG(grp);
        if ((t & 1) && grp + 1 < ngrp) PFG(grp + 1);   // VGPR loads BEFORE glds

        const unsigned short* Ab;
        const uint32_t* Bpb;
        if constexpr (WS) {
            const int buf = t % 3;
            Ab = As + buf * ASZ;
            Bpb = Bp + buf * BPSZ;
            if (t + 2 < NT) {                       // stage t+2 (2-deep pipeline)
                const int sb = (t + 2) % 3;
                GLDSB((t + 2) * BK, Bp + sb * BPSZ);
                GLDSA((t + 2) * BK, As + sb * ASZ);
            }
        } else {
            const int buf = t & 1;
            Ab = As + buf * ASZ;
            Bpb = Bp + buf * BPSZ;
            if (t + 1 < NT) {
                GLDSB((t + 1) * BK, Bp + (buf ^ 1) * BPSZ);
                LOADA((t + 1) * BK);
            }
        }

        // compute: 4 quadrants, plain code — compiler schedules, waves drift
        DEQB(Bpb, bfA, 0);
        RDA(Ab, 0, 0);
        MFMAQ(bfA, 0);
        RDA(Ab, 1, 0);
        MFMAQ(bfA, 1);
        DEQB(Bpb, bfB, 1);
        RDA(Ab, 0, 1);
        MFMAQ(bfB, 0);
        RDA(Ab, 1, 1);
        MFMAQ(bfB, 1);

        if constexpr (WS) {
            // counted wait: <=5 outstanding = exactly THIS tile's glds (4A+1B);
            // all older (t+1's glds, PFG) retired => t+1 visible after barrier.
            asm volatile("s_waitcnt vmcnt(5)" ::: "memory");
            __builtin_amdgcn_s_barrier();
        } else {
            if (t + 1 < NT) { WA(As + ((t & 1) ^ 1) * ASZ, 0); WA(As + ((t & 1) ^ 1) * ASZ, 1);
                              WA(As + ((t & 1) ^ 1) * ASZ, 2); WA(As + ((t & 1) ^ 1) * ASZ, 3); }
            __syncthreads();
        }
    }

    // epilogue
    const int r4 = (lane >> 4) << 2;
    #pragma unroll
    for (int n = 0; n < 4; ++n) {
        int col = n0 + wc * 64 + n * 16 + lrow;
        float bv = bias[col];
        #pragma unroll
        for (int m = 0; m < 8; ++m) {
            size_t rbase = (size_t)(m0 + wr * 128 + m * 16 + r4) * N + col;
            #pragma unroll
            for (int e = 0; e < 4; ++e)
                __builtin_nontemporal_store(acc[m][n][e] + bv, &out[rbase + (size_t)e * N]);
        }
    }
}

extern "C" void kernel_launch(void* const* d_in, const int* in_sizes, int n_in,
                              void* d_out, int out_size, void* d_ws, size_t ws_size,
                              hipStream_t stream) {
    const float* x   = (const float*)d_in[0];
    const int*   qwp = (const int*)d_in[1];
    const int*   qzp = (const int*)d_in[2];
    const float* scp = (const float*)d_in[3];
    const float* bp  = (const float*)d_in[4];
    float* outp = (float*)d_out;

    const int N = in_sizes[4];                 // 4096 (O)
    const int K = (in_sizes[1] / N) * 8;       // 4096 (I)
    const int M = in_sizes[0] / K;             // 8192 (B)

    dim3 grid((M / BM) * (N / BN));            // 512
    dim3 block(512);

    const size_t need = (size_t)M * K * 2;
    if (ws_size >= need) {
        unsigned short* xh = (unsigned short*)d_ws;
        int nchunk = M * (K / 8);
        convert_x_kernel<<<dim3((nchunk + 255) / 256), dim3(256), 0, stream>>>(
            x, xh, M, K);
        // LDS: 3 x (A 32 KB) + 3 x (Bp 8 KB) = 120 KB
        const int ldsbytes = 3 * BM * BK * 2 + 3 * BN * (BK / 8) * 4;
        (void)hipFuncSetAttribute(
            reinterpret_cast<const void*>(&awq_gemm_kernel<true>),
            hipFuncAttributeMaxDynamicSharedMemorySize, ldsbytes);
        awq_gemm_kernel<true><<<grid, block, ldsbytes, stream>>>(
            x, xh, qwp, qzp, scp, bp, outp, M, N, K);
    } else {
        const int ldsbytes = 2 * BM * BK * 2 + 2 * BN * (BK / 8) * 4;
        (void)hipFuncSetAttribute(
            reinterpret_cast<const void*>(&awq_gemm_kernel<false>),
            hipFuncAttributeMaxDynamicSharedMemorySize, ldsbytes);
        awq_gemm_kernel<false><<<grid, block, ldsbytes, stream>>>(
            x, nullptr, qwp, qzp, scp, bp, outp, M, N, K);
    }
}

// Round 12
// 323.465 us; speedup vs baseline: 1.6978x; 1.0283x over previous
//
#include <hip/hip_runtime.h>
#include <stdint.h>

// AWQ 4-bit dequant GEMM: out[M,N] = x[M,K] @ W[N,K]^T + bias
// Path 2 (ws >= X+W): prepass x->fp16 AND W->fp16 into d_ws (pair-permuted,
//   period-4 XOR swizzle baked). GEMM = pure fp16: BM=BN=256, BK=32, 512 thr,
//   both operands via global_load_lds_dwordx4, TRIPLE-buffered 96 KB LDS,
//   stage t+2, tile-end s_waitcnt vmcnt(4) (counted; drain-0 only in tail),
//   one s_barrier/tile. Zero in-loop dequant VALU, zero ds_writes, ~0 bank
//   conflicts (2-way max on b128 frag reads).
// Path 1 (ws >= X): R11 kernel (packed-B LDS + frag-time dequant). Path 0: reg-staged.

#define BM 256
#define BN 256

typedef _Float16 f16x2 __attribute__((ext_vector_type(2)));
typedef _Float16 f16x8 __attribute__((ext_vector_type(8)));
typedef float f32x4 __attribute__((ext_vector_type(4)));
typedef unsigned int u32x4 __attribute__((ext_vector_type(4)));

// ---------- prepass (path 2): x -> fp16, pair-perm, period-4 swizzle ----------
// dest chunk cc (8 elems) <- source chunk (cc&~3) | ((cc&3) ^ ((r>>1)&3))
__global__ void convert_x2_kernel(const float* __restrict__ x,
                                  unsigned short* __restrict__ xh,
                                  int M, int K) {
    int g = blockIdx.x * blockDim.x + threadIdx.x;
    int kc = K >> 3;
    if (g >= M * kc) return;
    int r  = g / kc;
    int cc = g - r * kc;
    int csrc = (cc & ~3) | ((cc & 3) ^ ((r >> 1) & 3));
    const float* p = x + (size_t)r * K + (csrc << 3);
    float4 f0 = *reinterpret_cast<const float4*>(p);
    float4 f1 = *reinterpret_cast<const float4*>(p + 4);
    u32x4 o;
    o.x = __builtin_bit_cast(uint32_t, __builtin_amdgcn_cvt_pkrtz(f0.x, f1.x));
    o.y = __builtin_bit_cast(uint32_t, __builtin_amdgcn_cvt_pkrtz(f0.y, f1.y));
    o.z = __builtin_bit_cast(uint32_t, __builtin_amdgcn_cvt_pkrtz(f0.z, f1.z));
    o.w = __builtin_bit_cast(uint32_t, __builtin_amdgcn_cvt_pkrtz(f0.w, f1.w));
    u32x4* dst = reinterpret_cast<u32x4*>(xh + (size_t)r * K + (cc << 3));
    __builtin_nontemporal_store(o, dst);
}

// ---------- prepass (path 2): W (int4) -> fp16 dequant, pair-perm, swizzle ----
__global__ void convert_w2_kernel(const int* __restrict__ qw,
                                  const int* __restrict__ qz,
                                  const float* __restrict__ sc,
                                  unsigned short* __restrict__ wh,
                                  int Nrows, int K) {
    int g = blockIdx.x * blockDim.x + threadIdx.x;
    int kc = K >> 3;
    if (g >= Nrows * kc) return;
    int o  = g / kc;
    int cc = g - o * kc;
    int ngrp = K >> 7, nzw = ngrp >> 3;
    int grp = cc >> 4;                       // 16 dwords (128 k) per group
    float s = sc[(size_t)o * ngrp + grp];
    uint32_t z = ((uint32_t)qz[(size_t)o * nzw + (grp >> 3)] >> ((grp & 7) << 2)) & 0xF;
    uint32_t u = (uint32_t)qw[(size_t)o * kc + cc];
    _Float16 hs = (_Float16)s;
    _Float16 hz = (_Float16)(1024.0f + (float)z);   // exact in fp16
    f16x2 s2 = {hs, hs}, z2 = {hz, hz};
    const uint32_t MK = 0x000F000Fu, MG = 0x64006400u;
    uint32_t p0 = (u & MK) | MG;
    uint32_t p1 = ((u >> 4) & MK) | MG;
    uint32_t p2 = ((u >> 8) & MK) | MG;
    uint32_t p3 = ((u >> 12) & MK) | MG;
    u32x4 ov;
    ov.x = __builtin_bit_cast(uint32_t, (__builtin_bit_cast(f16x2, p0) - z2) * s2);
    ov.y = __builtin_bit_cast(uint32_t, (__builtin_bit_cast(f16x2, p1) - z2) * s2);
    ov.z = __builtin_bit_cast(uint32_t, (__builtin_bit_cast(f16x2, p2) - z2) * s2);
    ov.w = __builtin_bit_cast(uint32_t, (__builtin_bit_cast(f16x2, p3) - z2) * s2);
    int cdst = (cc & ~3) | ((cc & 3) ^ ((o >> 1) & 3));
    u32x4* dst = reinterpret_cast<u32x4*>(wh + (size_t)o * K + (cdst << 3));
    __builtin_nontemporal_store(ov, dst);
}

// ---------- path 2 GEMM: pure fp16, BK=32, triple-buffer, counted vmcnt ------
__global__ __launch_bounds__(512, 2) void awq_gemm2_kernel(
    const unsigned short* __restrict__ xh,
    const unsigned short* __restrict__ wh,
    const float* __restrict__ bias,
    float* __restrict__ out,
    int M, int N, int K)
{
    extern __shared__ __align__(16) unsigned short lds[];
    const int TSZ = 256 * 32;                 // 8192 u16 per buffer
    unsigned short* As = lds;                 // [3][TSZ]
    unsigned short* Bs = lds + 3 * TSZ;       // [3][TSZ]

    const int tid  = threadIdx.x;
    const int lane = tid & 63;
    const int wave = tid >> 6;
    const int wr   = wave >> 2;               // 128-row half
    const int wc   = wave & 3;                // 64-col quarter
    const int lrow = lane & 15;
    // frag-read chunk (with period-4 inverse swizzle), in elements
    const int cswz = (((lane >> 4) ^ ((lrow >> 1) & 3)) << 3);

    const int cpx = gridDim.x >> 3;
    const int bid = (blockIdx.x & 7) * cpx + (blockIdx.x >> 3);
    const int ntn = N / BN;
    const int m0 = (bid / ntn) * BM;
    const int n0 = (bid % ntn) * BN;
    const int NT = K / 32;

    f32x4 acc[8][4];
    #pragma unroll
    for (int m = 0; m < 8; ++m)
        #pragma unroll
        for (int n = 0; n < 4; ++n)
            #pragma unroll
            for (int e = 0; e < 4; ++e) acc[m][n][e] = 0.f;

    // 2 glds_dwordx4 per wave: rows wave*32..+31, 32 k (64 B) each row
    auto GLDS = [&](const unsigned short* src, int row0, int kt, unsigned short* dst) {
        #pragma unroll
        for (int i = 0; i < 2; ++i) {
            int row = wave * 32 + i * 16 + (lane >> 2);
            const unsigned short* g = src + (size_t)(row0 + row) * K + kt + ((lane & 3) << 3);
            unsigned short* d = dst + row * 32 + ((lane & 3) << 3);   // = base + lane*16B
            __builtin_amdgcn_global_load_lds(
                (const __attribute__((address_space(1))) unsigned int*)g,
                (__attribute__((address_space(3))) unsigned int*)d, 16, 0, 0);
        }
    };

    // ---- prologue: stage tiles 0,1 into buf 0,1; full drain; barrier
    GLDS(xh, m0, 0, As);
    GLDS(wh, n0, 0, Bs);
    if (NT > 1) {
        GLDS(xh, m0, 32, As + TSZ);
        GLDS(wh, n0, 32, Bs + TSZ);
    }
    asm volatile("s_waitcnt vmcnt(0)" ::: "memory");
    __syncthreads();

    for (int t = 0; t < NT; ++t) {
        const int buf = t % 3;
        const unsigned short* Ab = As + buf * TSZ;
        const unsigned short* Bb = Bs + buf * TSZ;
        const bool deep = (t + 2 < NT);
        if (deep) {
            const int sb = (t + 2) % 3;
            GLDS(xh, m0, (t + 2) * 32, As + sb * TSZ);
            GLDS(wh, n0, (t + 2) * 32, Bs + sb * TSZ);
        }

        f16x8 bf[4], af[8];
        #pragma unroll
        for (int n = 0; n < 4; ++n) {
            int row = wc * 64 + n * 16 + lrow;
            bf[n] = __builtin_bit_cast(f16x8,
                    *reinterpret_cast<const uint4*>(&Bb[row * 32 + cswz]));
        }
        #pragma unroll
        for (int m = 0; m < 8; ++m) {
            int row = wr * 128 + m * 16 + lrow;
            af[m] = __builtin_bit_cast(f16x8,
                    *reinterpret_cast<const uint4*>(&Ab[row * 32 + cswz]));
        }
        #pragma unroll
        for (int m = 0; m < 8; ++m)
            #pragma unroll
            for (int n = 0; n < 4; ++n)
                acc[m][n] = __builtin_amdgcn_mfma_f32_16x16x32_f16(
                    af[m], bf[n], acc[m][n], 0, 0, 0);

        // counted wait: steady state leaves t+2's 4 glds in flight (t+1's are
        // older -> retired). Tail (no t+2 staged): newest are t+1's -> drain 0.
        if (deep) { asm volatile("s_waitcnt vmcnt(4)" ::: "memory"); }
        else      { asm volatile("s_waitcnt vmcnt(0)" ::: "memory"); }
        __builtin_amdgcn_s_barrier();
    }

    // epilogue: C frag col=lane&15, row=(lane>>4)*4+e
    const int r4 = (lane >> 4) << 2;
    #pragma unroll
    for (int n = 0; n < 4; ++n) {
        int col = n0 + wc * 64 + n * 16 + lrow;
        float bv = bias[col];
        #pragma unroll
        for (int m = 0; m < 8; ++m) {
            size_t rbase = (size_t)(m0 + wr * 128 + m * 16 + r4) * N + col;
            #pragma unroll
            for (int e = 0; e < 4; ++e)
                __builtin_nontemporal_store(acc[m][n][e] + bv, &out[rbase + (size_t)e * N]);
        }
    }
}

// ================= path 1 / 0: R11 kernel (unchanged) =======================
#define BK 64

__global__ void convert_x_kernel(const float* __restrict__ x,
                                 unsigned short* __restrict__ xh,
                                 int M, int K) {
    int g = blockIdx.x * blockDim.x + threadIdx.x;
    int kc = K >> 3;
    if (g >= M * kc) return;
    int r  = g / kc;
    int cc = g - r * kc;
    int tile = cc >> 3;
    int cpos = (cc & 7) << 3;
    int sw   = (r & 7) << 3;
    const float* p = x + (size_t)r * K + (tile << 6) + (cpos ^ sw);
    float4 f0 = *reinterpret_cast<const float4*>(p);
    float4 f1 = *reinterpret_cast<const float4*>(p + 4);
    u32x4 o;
    o.x = __builtin_bit_cast(uint32_t, __builtin_amdgcn_cvt_pkrtz(f0.x, f1.x));
    o.y = __builtin_bit_cast(uint32_t, __builtin_amdgcn_cvt_pkrtz(f0.y, f1.y));
    o.z = __builtin_bit_cast(uint32_t, __builtin_amdgcn_cvt_pkrtz(f0.z, f1.z));
    o.w = __builtin_bit_cast(uint32_t, __builtin_amdgcn_cvt_pkrtz(f0.w, f1.w));
    u32x4* dst = reinterpret_cast<u32x4*>(xh + (size_t)r * K + (tile << 6) + cpos);
    __builtin_nontemporal_store(o, dst);
}

template <bool WS>
__global__ __launch_bounds__(512, 2) void awq_gemm_kernel(
    const float* __restrict__ x,
    const unsigned short* __restrict__ xh,
    const int*   __restrict__ qw,
    const int*   __restrict__ qz,
    const float* __restrict__ sc,
    const float* __restrict__ bias,
    float*       __restrict__ out,
    int M, int N, int K)
{
    extern __shared__ __align__(16) unsigned short lds[];
    const int ASZ  = BM * BK;
    const int BPSZ = BN * (BK / 8);
    const int NBUF = WS ? 3 : 2;
    unsigned short* As = lds;
    uint32_t* Bp = reinterpret_cast<uint32_t*>(lds + NBUF * ASZ);

    const int tid  = threadIdx.x;
    const int lane = tid & 63;
    const int wave = tid >> 6;
    const int wr   = wave >> 2;
    const int wc   = wave & 3;
    const int lrow = lane & 15;
    const int lko  = (lane >> 4) << 3;
    const int swr  = (lrow & 7) << 3;

    const int cpx = gridDim.x >> 3;
    const int bid = (blockIdx.x & 7) * cpx + (blockIdx.x >> 3);
    const int ntn = N / BN;
    const int m0 = (bid / ntn) * BM;
    const int n0 = (bid % ntn) * BN;

    const int ngrp = K >> 7;
    const int nzw  = ngrp >> 3;
    const int kw   = K >> 3;
    const int NT   = K / BK;

    const int r_s = tid >> 1;
    const int kh  = tid & 1;
    const int sws = (r_s & 7) << 3;

    f32x4 acc[8][4];
    #pragma unroll
    for (int m = 0; m < 8; ++m)
        #pragma unroll
        for (int n = 0; n < 4; ++n)
            #pragma unroll
            for (int e = 0; e < 4; ++e) acc[m][n][e] = 0.f;

    float    sc_pf[4];
    uint32_t zq_pf[4];
    f16x2    ss[4], zz[4];
    auto PFG = [&](int grp) {
        #pragma unroll
        for (int n = 0; n < 4; ++n) {
            int og = n0 + wc * 64 + n * 16 + lrow;
            sc_pf[n] = sc[(size_t)og * ngrp + grp];
            zq_pf[n] = (uint32_t)qz[(size_t)og * nzw + (grp >> 3)];
        }
    };
    auto SETG = [&](int grp) {
        #pragma unroll
        for (int n = 0; n < 4; ++n) {
            _Float16 s = (_Float16)sc_pf[n];
            uint32_t z = (zq_pf[n] >> ((grp & 7) << 2)) & 0xF;
            _Float16 Z = (_Float16)(float)(1024u + z);
            ss[n][0] = s; ss[n][1] = s;
            zz[n][0] = Z; zz[n][1] = Z;
        }
    };

    float4 a32[8];

    auto GLDSB = [&](int kt, uint32_t* Bw) {
        int row = tid >> 1;
        const int* g = qw + (size_t)(n0 + row) * kw + (kt >> 3) + (tid & 1) * 4;
        uint32_t* d = Bw + row * 8 + (tid & 1) * 4;
        __builtin_amdgcn_global_load_lds(
            (const __attribute__((address_space(1))) unsigned int*)g,
            (__attribute__((address_space(3))) unsigned int*)d, 16, 0, 0);
    };
    auto GLDSA = [&](int kt, unsigned short* Aw) {
        #pragma unroll
        for (int i = 0; i < 4; ++i) {
            int row = wave * 32 + i * 8 + (lane >> 3);
            const unsigned short* g = xh + (size_t)(m0 + row) * K + kt + ((lane & 7) << 3);
            unsigned short* d = Aw + row * BK + ((lane & 7) << 3);
            __builtin_amdgcn_global_load_lds(
                (const __attribute__((address_space(1))) unsigned int*)g,
                (__attribute__((address_space(3))) unsigned int*)d, 16, 0, 0);
        }
    };
    auto LOADA = [&](int kt) {
        const float* p = x + (size_t)(m0 + r_s) * K + kt + kh * 32;
        #pragma unroll
        for (int i = 0; i < 8; ++i)
            a32[i] = *reinterpret_cast<const float4*>(p + 4 * i);
    };
    auto WA = [&](unsigned short* dst, int c) {
        uint4 o;
        o.x = __builtin_bit_cast(uint32_t, __builtin_amdgcn_cvt_pkrtz(a32[2*c].x, a32[2*c+1].x));
        o.y = __builtin_bit_cast(uint32_t, __builtin_amdgcn_cvt_pkrtz(a32[2*c].y, a32[2*c+1].y));
        o.z = __builtin_bit_cast(uint32_t, __builtin_amdgcn_cvt_pkrtz(a32[2*c].z, a32[2*c+1].z));
        o.w = __builtin_bit_cast(uint32_t, __builtin_amdgcn_cvt_pkrtz(a32[2*c].w, a32[2*c+1].w));
        int kcol = kh * 32 + 8 * c;
        *reinterpret_cast<uint4*>(&dst[r_s * BK + (kcol ^ sws)]) = o;
    };

    f16x8 af[4], bfA[4], bfB[4];
    auto RDA = [&](const unsigned short* Ab, int mh, int kk) {
        #pragma unroll
        for (int m = 0; m < 4; ++m) {
            int arow = wr * 128 + (mh * 4 + m) * 16 + lrow;
            int idx = arow * BK + ((kk * 32 + lko) ^ swr);
            af[m] = __builtin_bit_cast(f16x8, *reinterpret_cast<const uint4*>(&Ab[idx]));
        }
    };
    auto DEQB = [&](const uint32_t* Bpb, f16x8* b, int kk) {
        const int dcol = kk * 4 + (lane >> 4);
        const uint32_t MK = 0x000F000Fu, MG = 0x64006400u;
        #pragma unroll
        for (int n = 0; n < 4; ++n) {
            int brow = wc * 64 + n * 16 + lrow;
            uint32_t u = Bpb[brow * 8 + dcol];
            uint32_t p0 = (u & MK) | MG;
            uint32_t p1 = ((u >> 4) & MK) | MG;
            uint32_t p2 = ((u >> 8) & MK) | MG;
            uint32_t p3 = ((u >> 12) & MK) | MG;
            u32x4 o;
            o.x = __builtin_bit_cast(uint32_t, (__builtin_bit_cast(f16x2, p0) - zz[n]) * ss[n]);
            o.y = __builtin_bit_cast(uint32_t, (__builtin_bit_cast(f16x2, p1) - zz[n]) * ss[n]);
            o.z = __builtin_bit_cast(uint32_t, (__builtin_bit_cast(f16x2, p2) - zz[n]) * ss[n]);
            o.w = __builtin_bit_cast(uint32_t, (__builtin_bit_cast(f16x2, p3) - zz[n]) * ss[n]);
            b[n] = __builtin_bit_cast(f16x8, o);
        }
    };
    auto MFMAQ = [&](f16x8* bf, int mh) {
        #pragma unroll
        for (int m_ = 0; m_ < 4; ++m_)
            #pragma unroll
            for (int n_ = 0; n_ < 4; ++n_)
                acc[mh * 4 + m_][n_] = __builtin_amdgcn_mfma_f32_16x16x32_f16(
                    af[m_], bf[n_], acc[mh * 4 + m_][n_], 0, 0, 0);
    };

    PFG(0);
    if constexpr (WS) {
        GLDSB(0, Bp);
        GLDSA(0, As);
        if (NT > 1) { GLDSB(BK, Bp + BPSZ); GLDSA(BK, As + ASZ); }
        asm volatile("s_waitcnt vmcnt(0)" ::: "memory");
        SETG(0);
        __syncthreads();
    } else {
        GLDSB(0, Bp);
        LOADA(0);
        asm volatile("s_waitcnt vmcnt(0)" ::: "memory");
        #pragma unroll
        for (int c = 0; c < 4; ++c) WA(As, c);
        SETG(0);
        __syncthreads();
    }

    for (int t = 0; t < NT; ++t) {
        const int grp = t >> 1;
        if (t && !(t & 1)) SETG(grp);
        if ((t & 1) && grp + 1 < ngrp) PFG(grp + 1);

        const unsigned short* Ab;
        const uint32_t* Bpb;
        if constexpr (WS) {
            const int buf = t % 3;
            Ab = As + buf * ASZ;
            Bpb = Bp + buf * BPSZ;
            if (t + 2 < NT) {
                const int sb = (t + 2) % 3;
                GLDSB((t + 2) * BK, Bp + sb * BPSZ);
                GLDSA((t + 2) * BK, As + sb * ASZ);
            }
        } else {
            const int buf = t & 1;
            Ab = As + buf * ASZ;
            Bpb = Bp + buf * BPSZ;
            if (t + 1 < NT) {
                GLDSB((t + 1) * BK, Bp + (buf ^ 1) * BPSZ);
                LOADA((t + 1) * BK);
            }
        }

        DEQB(Bpb, bfA, 0);
        RDA(Ab, 0, 0);
        MFMAQ(bfA, 0);
        RDA(Ab, 1, 0);
        MFMAQ(bfA, 1);
        DEQB(Bpb, bfB, 1);
        RDA(Ab, 0, 1);
        MFMAQ(bfB, 0);
        RDA(Ab, 1, 1);
        MFMAQ(bfB, 1);

        if constexpr (WS) {
            if (t + 2 < NT) { asm volatile("s_waitcnt vmcnt(5)" ::: "memory"); }
            else            { asm volatile("s_waitcnt vmcnt(0)" ::: "memory"); }
            __builtin_amdgcn_s_barrier();
        } else {
            if (t + 1 < NT) { WA(As + ((t & 1) ^ 1) * ASZ, 0); WA(As + ((t & 1) ^ 1) * ASZ, 1);
                              WA(As + ((t & 1) ^ 1) * ASZ, 2); WA(As + ((t & 1) ^ 1) * ASZ, 3); }
            __syncthreads();
        }
    }

    const int r4 = (lane >> 4) << 2;
    #pragma unroll
    for (int n = 0; n < 4; ++n) {
        int col = n0 + wc * 64 + n * 16 + lrow;
        float bv = bias[col];
        #pragma unroll
        for (int m = 0; m < 8; ++m) {
            size_t rbase = (size_t)(m0 + wr * 128 + m * 16 + r4) * N + col;
            #pragma unroll
            for (int e = 0; e < 4; ++e)
                __builtin_nontemporal_store(acc[m][n][e] + bv, &out[rbase + (size_t)e * N]);
        }
    }
}

extern "C" void kernel_launch(void* const* d_in, const int* in_sizes, int n_in,
                              void* d_out, int out_size, void* d_ws, size_t ws_size,
                              hipStream_t stream) {
    const float* x   = (const float*)d_in[0];
    const int*   qwp = (const int*)d_in[1];
    const int*   qzp = (const int*)d_in[2];
    const float* scp = (const float*)d_in[3];
    const float* bp  = (const float*)d_in[4];
    float* outp = (float*)d_out;

    const int N = in_sizes[4];                 // 4096 (O)
    const int K = (in_sizes[1] / N) * 8;       // 4096 (I)
    const int M = in_sizes[0] / K;             // 8192 (B)

    dim3 grid((M / BM) * (N / BN));            // 512
    dim3 block(512);

    const size_t needX = (size_t)M * K * 2;
    const size_t needW = (size_t)N * K * 2;

    if (ws_size >= needX + needW) {
        // ---- path 2: both operands pre-converted, pure fp16 GEMM
        unsigned short* xh = (unsigned short*)d_ws;
        unsigned short* wh = xh + (size_t)M * K;
        int ncx = M * (K / 8), ncw = N * (K / 8);
        convert_x2_kernel<<<dim3((ncx + 255) / 256), dim3(256), 0, stream>>>(x, xh, M, K);
        convert_w2_kernel<<<dim3((ncw + 255) / 256), dim3(256), 0, stream>>>(qwp, qzp, scp, wh, N, K);
        const int ldsbytes = 6 * 256 * 32 * 2;   // 96 KB
        (void)hipFuncSetAttribute(
            reinterpret_cast<const void*>(&awq_gemm2_kernel),
            hipFuncAttributeMaxDynamicSharedMemorySize, ldsbytes);
        awq_gemm2_kernel<<<grid, block, ldsbytes, stream>>>(xh, wh, bp, outp, M, N, K);
    } else if (ws_size >= needX) {
        unsigned short* xh = (unsigned short*)d_ws;
        int nchunk = M * (K / 8);
        convert_x_kernel<<<dim3((nchunk + 255) / 256), dim3(256), 0, stream>>>(x, xh, M, K);
        const int ldsbytes = 3 * BM * BK * 2 + 3 * BN * (BK / 8) * 4;
        (void)hipFuncSetAttribute(
            reinterpret_cast<const void*>(&awq_gemm_kernel<true>),
            hipFuncAttributeMaxDynamicSharedMemorySize, ldsbytes);
        awq_gemm_kernel<true><<<grid, block, ldsbytes, stream>>>(
            x, xh, qwp, qzp, scp, bp, outp, M, N, K);
    } else {
        const int ldsbytes = 2 * BM * BK * 2 + 2 * BN * (BK / 8) * 4;
        (void)hipFuncSetAttribute(
            reinterpret_cast<const void*>(&awq_gemm_kernel<false>),
            hipFuncAttributeMaxDynamicSharedMemorySize, ldsbytes);
        awq_gemm_kernel<false><<<grid, block, ldsbytes, stream>>>(
            x, nullptr, qwp, qzp, scp, bp, outp, M, N, K);
    }
}